// Round 1
// baseline (540.691 us; speedup 1.0000x reference)
//
#include <hip/hip_runtime.h>

#define Bq 4
#define Nq 512
#define Dq 128

constexpr float LEAKY = 0.01f;
constexpr float LN_EPS = 1e-5f;

typedef float f4 __attribute__((ext_vector_type(4)));

// ---------------- Kernel 1: LayerNorm + attention scores ----------------
// One wave (64 lanes) per (b,n) row; lane handles 2 of the D=128 elements.
// Block = 256 threads = 4 rows.
__global__ void __launch_bounds__(256) scores_kernel(
    const float* __restrict__ emb, const float* __restrict__ att_w,
    const float* __restrict__ gamma, const float* __restrict__ beta,
    float* __restrict__ sq, float* __restrict__ sk)
{
    const int wave = threadIdx.x >> 6;
    const int lane = threadIdx.x & 63;
    const int row  = blockIdx.x * 4 + wave;          // [0, B*N)

    const float2 x = ((const float2*)(emb + (size_t)row * Dq))[lane];

    float s = x.x + x.y;
    #pragma unroll
    for (int off = 32; off > 0; off >>= 1) s += __shfl_xor(s, off);
    const float mu = s * (1.0f / Dq);

    const float d0 = x.x - mu, d1 = x.y - mu;
    float v = d0 * d0 + d1 * d1;
    #pragma unroll
    for (int off = 32; off > 0; off >>= 1) v += __shfl_xor(v, off);
    const float rstd = rsqrtf(v * (1.0f / Dq) + LN_EPS);

    const float2 g  = ((const float2*)gamma)[lane];
    const float2 bt = ((const float2*)beta)[lane];
    const float ln0 = d0 * rstd * g.x + bt.x;
    const float ln1 = d1 * rstd * g.y + bt.y;

    const float2 wq = ((const float2*)att_w)[lane];
    const float2 wk = ((const float2*)(att_w + Dq))[lane];
    float pq = ln0 * wq.x + ln1 * wq.y;
    float pk = ln0 * wk.x + ln1 * wk.y;
    #pragma unroll
    for (int off = 32; off > 0; off >>= 1) {
        pq += __shfl_xor(pq, off);
        pk += __shfl_xor(pk, off);
    }
    if (lane == 0) { sq[row] = pq; sk[row] = pk; }
}

// ---------------- Kernel 2: leaky-relu logits + softmax over j ----------------
// One block (256 threads) per (b,i) row; each thread handles 2 j's.
// alphas is a pure output (never re-read) -> non-temporal stores.
__global__ void __launch_bounds__(256) softmax_kernel(
    const float* __restrict__ sq, const float* __restrict__ sk,
    const float* __restrict__ att_b, float* __restrict__ alphas)
{
    const int row = blockIdx.x;       // b*N + i
    const int b   = row >> 9;         // N = 512
    const int t   = threadIdx.x;
    const int wave = t >> 6, lane = t & 63;

    const float si = sq[row] + att_b[0];
    const float* skb = sk + b * Nq;

    float x0 = si + skb[t];
    float x1 = si + skb[t + 256];
    const float l0 = (x0 >= 0.0f) ? x0 : LEAKY * x0;
    const float l1 = (x1 >= 0.0f) ? x1 : LEAKY * x1;

    __shared__ float redm[4];
    __shared__ float reds[4];

    float m = fmaxf(l0, l1);
    #pragma unroll
    for (int off = 32; off > 0; off >>= 1) m = fmaxf(m, __shfl_xor(m, off));
    if (lane == 0) redm[wave] = m;
    __syncthreads();
    m = fmaxf(fmaxf(redm[0], redm[1]), fmaxf(redm[2], redm[3]));

    const float e0 = __expf(l0 - m);
    const float e1 = __expf(l1 - m);
    float s = e0 + e1;
    #pragma unroll
    for (int off = 32; off > 0; off >>= 1) s += __shfl_xor(s, off);
    if (lane == 0) reds[wave] = s;
    __syncthreads();
    s = reds[0] + reds[1] + reds[2] + reds[3];

    const float inv = 1.0f / s;
    float* arow = alphas + (size_t)row * Nq;
    __builtin_nontemporal_store(e0 * inv, arow + t);
    __builtin_nontemporal_store(e1 * inv, arow + t + 256);
}

// ---------------- Kernel 3: value outer product ----------------
// One block (256 threads) per (b, i-pair): IG=2 output rows per block, so each
// emb[b,j] read from L2 is reused for 2 output rows (halves L2 read traffic).
// value[b,i,j,:] = emb[b,i,:] * emb[b,j,:] is a pure 512 MB streaming output:
// non-temporal stores keep it out of L2 (no write-allocate/RFO, no thrash of
// the L2-resident emb[b] panel).
// Thread t: d4 = t&31 (float4 index over D=128), jl = t>>5 (8 j's per iter).
// Each nt store instruction is 1 KB contiguous per wave -> full-line writes.
#define IG 2

__global__ void __launch_bounds__(256) value_kernel(
    const float* __restrict__ emb, float* __restrict__ value)
{
    const int g  = blockIdx.x;            // [0, B*N/IG)
    const int b  = g >> 8;                // Nq/IG = 256 groups per batch
    const int i0 = (g & 255) * IG;
    const int t  = threadIdx.x;
    const int d4 = t & 31;
    const int jl = t >> 5;

    const f4* __restrict__ eb4 = (const f4*)(emb + (size_t)b * Nq * Dq);
    const f4 a0 = eb4[(i0 + 0) * 32 + d4];
    const f4 a1 = eb4[(i0 + 1) * 32 + d4];

    f4* __restrict__ out0 = (f4*)(value + (size_t)(b * Nq + i0) * Nq * Dq);
    f4* __restrict__ out1 = out0 + (size_t)Nq * 32;

    #pragma unroll 4
    for (int j0 = 0; j0 < Nq; j0 += 8) {
        const int j = j0 + jl;
        const f4 v = eb4[j * 32 + d4];
        __builtin_nontemporal_store(a0 * v, out0 + j * 32 + d4);
        __builtin_nontemporal_store(a1 * v, out1 + j * 32 + d4);
    }
}

extern "C" void kernel_launch(void* const* d_in, const int* in_sizes, int n_in,
                              void* d_out, int out_size, void* d_ws, size_t ws_size,
                              hipStream_t stream) {
    const float* emb    = (const float*)d_in[0];
    const float* att_w  = (const float*)d_in[1];
    const float* att_b  = (const float*)d_in[2];
    const float* gamma  = (const float*)d_in[3];
    const float* beta   = (const float*)d_in[4];

    float* alphas = (float*)d_out;                              // B*N*N
    float* value  = (float*)d_out + (size_t)Bq * Nq * Nq;       // B*N*N*D

    float* sq = (float*)d_ws;           // B*N
    float* sk = sq + Bq * Nq;           // B*N

    scores_kernel<<<Bq * Nq / 4, 256, 0, stream>>>(emb, att_w, gamma, beta, sq, sk);
    softmax_kernel<<<Bq * Nq, 256, 0, stream>>>(sq, sk, att_b, alphas);
    value_kernel<<<Bq * Nq / IG, 256, 0, stream>>>(emb, value);
}

// Round 2
// 537.360 us; speedup vs baseline: 1.0062x; 1.0062x over previous
//
#include <hip/hip_runtime.h>

#define Bq 4
#define Nq 512
#define Dq 128

constexpr float LEAKY = 0.01f;
constexpr float LN_EPS = 1e-5f;

typedef float f4 __attribute__((ext_vector_type(4)));

// ---------------- Kernel 1: LayerNorm + attention scores ----------------
// One wave (64 lanes) per (b,n) row; lane handles 2 of the D=128 elements.
// Block = 256 threads = 4 rows.
__global__ void __launch_bounds__(256) scores_kernel(
    const float* __restrict__ emb, const float* __restrict__ att_w,
    const float* __restrict__ gamma, const float* __restrict__ beta,
    float* __restrict__ sq, float* __restrict__ sk)
{
    const int wave = threadIdx.x >> 6;
    const int lane = threadIdx.x & 63;
    const int row  = blockIdx.x * 4 + wave;          // [0, B*N)

    const float2 x = ((const float2*)(emb + (size_t)row * Dq))[lane];

    float s = x.x + x.y;
    #pragma unroll
    for (int off = 32; off > 0; off >>= 1) s += __shfl_xor(s, off);
    const float mu = s * (1.0f / Dq);

    const float d0 = x.x - mu, d1 = x.y - mu;
    float v = d0 * d0 + d1 * d1;
    #pragma unroll
    for (int off = 32; off > 0; off >>= 1) v += __shfl_xor(v, off);
    const float rstd = rsqrtf(v * (1.0f / Dq) + LN_EPS);

    const float2 g  = ((const float2*)gamma)[lane];
    const float2 bt = ((const float2*)beta)[lane];
    const float ln0 = d0 * rstd * g.x + bt.x;
    const float ln1 = d1 * rstd * g.y + bt.y;

    const float2 wq = ((const float2*)att_w)[lane];
    const float2 wk = ((const float2*)(att_w + Dq))[lane];
    float pq = ln0 * wq.x + ln1 * wq.y;
    float pk = ln0 * wk.x + ln1 * wk.y;
    #pragma unroll
    for (int off = 32; off > 0; off >>= 1) {
        pq += __shfl_xor(pq, off);
        pk += __shfl_xor(pk, off);
    }
    if (lane == 0) { sq[row] = pq; sk[row] = pk; }
}

// ---------------- Kernel 2: leaky-relu logits + softmax over j ----------------
// One block (256 threads) per (b,i) row; each thread handles 2 j's.
// alphas is a pure output (never re-read) -> non-temporal stores.
__global__ void __launch_bounds__(256) softmax_kernel(
    const float* __restrict__ sq, const float* __restrict__ sk,
    const float* __restrict__ att_b, float* __restrict__ alphas)
{
    const int row = blockIdx.x;       // b*N + i
    const int b   = row >> 9;         // N = 512
    const int t   = threadIdx.x;
    const int wave = t >> 6, lane = t & 63;

    const float si = sq[row] + att_b[0];
    const float* skb = sk + b * Nq;

    float x0 = si + skb[t];
    float x1 = si + skb[t + 256];
    const float l0 = (x0 >= 0.0f) ? x0 : LEAKY * x0;
    const float l1 = (x1 >= 0.0f) ? x1 : LEAKY * x1;

    __shared__ float redm[4];
    __shared__ float reds[4];

    float m = fmaxf(l0, l1);
    #pragma unroll
    for (int off = 32; off > 0; off >>= 1) m = fmaxf(m, __shfl_xor(m, off));
    if (lane == 0) redm[wave] = m;
    __syncthreads();
    m = fmaxf(fmaxf(redm[0], redm[1]), fmaxf(redm[2], redm[3]));

    const float e0 = __expf(l0 - m);
    const float e1 = __expf(l1 - m);
    float s = e0 + e1;
    #pragma unroll
    for (int off = 32; off > 0; off >>= 1) s += __shfl_xor(s, off);
    if (lane == 0) reds[wave] = s;
    __syncthreads();
    s = reds[0] + reds[1] + reds[2] + reds[3];

    const float inv = 1.0f / s;
    float* arow = alphas + (size_t)row * Nq;
    __builtin_nontemporal_store(e0 * inv, arow + t);
    __builtin_nontemporal_store(e1 * inv, arow + t + 256);
}

// ---------------- Kernel 3: value outer product ----------------
// One block (256 threads) per (b,i) row — 2048 blocks = 8 blocks/CU =
// 32 waves/CU (FULL occupancy; round-1's IG=2 halved this and was neutral,
// suggesting occupancy loss canceled the NT gain).
// value[b,i,j,:] = emb[b,i,:] * emb[b,j,:] is a pure 512 MiB streaming output:
// non-temporal stores keep it out of L2 (no write-allocate/RFO; emb[b] panel
// stays L2-resident for the j-reads).
// Thread t: d4 = t&31 (float4 over D=128), jl = t>>5 (8 j's per iteration);
// each wave store = 1 KB contiguous, 256-thread iteration = 4 KB contiguous.
__global__ void __launch_bounds__(256) value_kernel(
    const float* __restrict__ emb, float* __restrict__ value)
{
    const int row = blockIdx.x;       // b*N + i
    const int b   = row >> 9;
    const int t   = threadIdx.x;
    const int d4  = t & 31;
    const int jl  = t >> 5;

    const f4 a = ((const f4*)(emb + (size_t)row * Dq))[d4];
    const f4* __restrict__ eb4 = (const f4*)(emb + (size_t)b * Nq * Dq);
    f4* __restrict__ out = (f4*)(value + (size_t)row * Nq * Dq);

    #pragma unroll 8
    for (int j0 = 0; j0 < Nq; j0 += 8) {
        const int j = j0 + jl;
        const f4 v = eb4[j * 32 + d4];
        __builtin_nontemporal_store(a * v, out + j * 32 + d4);
    }
}

extern "C" void kernel_launch(void* const* d_in, const int* in_sizes, int n_in,
                              void* d_out, int out_size, void* d_ws, size_t ws_size,
                              hipStream_t stream) {
    const float* emb    = (const float*)d_in[0];
    const float* att_w  = (const float*)d_in[1];
    const float* att_b  = (const float*)d_in[2];
    const float* gamma  = (const float*)d_in[3];
    const float* beta   = (const float*)d_in[4];

    float* alphas = (float*)d_out;                              // B*N*N
    float* value  = (float*)d_out + (size_t)Bq * Nq * Nq;       // B*N*N*D

    float* sq = (float*)d_ws;           // B*N
    float* sk = sq + Bq * Nq;           // B*N

    scores_kernel<<<Bq * Nq / 4, 256, 0, stream>>>(emb, att_w, gamma, beta, sq, sk);
    softmax_kernel<<<Bq * Nq, 256, 0, stream>>>(sq, sk, att_b, alphas);
    value_kernel<<<Bq * Nq, 256, 0, stream>>>(emb, value);
}

// Round 5
// 536.598 us; speedup vs baseline: 1.0076x; 1.0014x over previous
//
#include <hip/hip_runtime.h>

#define Bq 4
#define Nq 512
#define Dq 128

constexpr float LEAKY = 0.01f;
constexpr float LN_EPS = 1e-5f;

typedef float f4 __attribute__((ext_vector_type(4)));

// ---------------- Kernel 1: LayerNorm + attention scores ----------------
// One wave (64 lanes) per (b,n) row; lane handles 2 of the D=128 elements.
// Block = 256 threads = 4 rows.
__global__ void __launch_bounds__(256) scores_kernel(
    const float* __restrict__ emb, const float* __restrict__ att_w,
    const float* __restrict__ gamma, const float* __restrict__ beta,
    float* __restrict__ sq, float* __restrict__ sk)
{
    const int wave = threadIdx.x >> 6;
    const int lane = threadIdx.x & 63;
    const int row  = blockIdx.x * 4 + wave;          // [0, B*N)

    const float2 x = ((const float2*)(emb + (size_t)row * Dq))[lane];

    float s = x.x + x.y;
    #pragma unroll
    for (int off = 32; off > 0; off >>= 1) s += __shfl_xor(s, off);
    const float mu = s * (1.0f / Dq);

    const float d0 = x.x - mu, d1 = x.y - mu;
    float v = d0 * d0 + d1 * d1;
    #pragma unroll
    for (int off = 32; off > 0; off >>= 1) v += __shfl_xor(v, off);
    const float rstd = rsqrtf(v * (1.0f / Dq) + LN_EPS);

    const float2 g  = ((const float2*)gamma)[lane];
    const float2 bt = ((const float2*)beta)[lane];
    const float ln0 = d0 * rstd * g.x + bt.x;
    const float ln1 = d1 * rstd * g.y + bt.y;

    const float2 wq = ((const float2*)att_w)[lane];
    const float2 wk = ((const float2*)(att_w + Dq))[lane];
    float pq = ln0 * wq.x + ln1 * wq.y;
    float pk = ln0 * wk.x + ln1 * wk.y;
    #pragma unroll
    for (int off = 32; off > 0; off >>= 1) {
        pq += __shfl_xor(pq, off);
        pk += __shfl_xor(pk, off);
    }
    if (lane == 0) { sq[row] = pq; sk[row] = pk; }
}

// ---------------- Kernel 2: leaky-relu logits + softmax over j ----------------
// One block (256 threads) per (b,i) row; each thread handles 2 j's.
__global__ void __launch_bounds__(256) softmax_kernel(
    const float* __restrict__ sq, const float* __restrict__ sk,
    const float* __restrict__ att_b, float* __restrict__ alphas)
{
    const int row = blockIdx.x;       // b*N + i
    const int b   = row >> 9;         // N = 512
    const int t   = threadIdx.x;
    const int wave = t >> 6, lane = t & 63;

    const float si = sq[row] + att_b[0];
    const float* skb = sk + b * Nq;

    float x0 = si + skb[t];
    float x1 = si + skb[t + 256];
    const float l0 = (x0 >= 0.0f) ? x0 : LEAKY * x0;
    const float l1 = (x1 >= 0.0f) ? x1 : LEAKY * x1;

    __shared__ float redm[4];
    __shared__ float reds[4];

    float m = fmaxf(l0, l1);
    #pragma unroll
    for (int off = 32; off > 0; off >>= 1) m = fmaxf(m, __shfl_xor(m, off));
    if (lane == 0) redm[wave] = m;
    __syncthreads();
    m = fmaxf(fmaxf(redm[0], redm[1]), fmaxf(redm[2], redm[3]));

    const float e0 = __expf(l0 - m);
    const float e1 = __expf(l1 - m);
    float s = e0 + e1;
    #pragma unroll
    for (int off = 32; off > 0; off >>= 1) s += __shfl_xor(s, off);
    if (lane == 0) reds[wave] = s;
    __syncthreads();
    s = reds[0] + reds[1] + reds[2] + reds[3];

    const float inv = 1.0f / s;
    float* arow = alphas + (size_t)row * Nq;
    __builtin_nontemporal_store(e0 * inv, arow + t);
    __builtin_nontemporal_store(e1 * inv, arow + t + 256);
}

// ---------------- Kernel 3: value outer product, 2-D tiled ----------------
// Rounds 0-2 showed value stuck at ~180 us (~3.0 TB/s) with a 1:1 load:store
// mix (512 MB of reads re-streamed by the 537 MB store stream thrashing L2).
// New decomposition: each block owns an 8-i x 64-j tile. Reads = 36 KB/block
// (74 MB total, 7x cut); stores unchanged. Instruction mix 1 load : 8 stores
// (fill-like). Grid = 256 i-groups x 8 j-tiles = 2048 blocks = 32 waves/CU.
// Thread t: d4 = t&31 (float4 over D=128), jl = t>>5 -> 8 j's per pass,
// 8 passes cover JT=64. Each wave store = 1 KB contiguous.
#define IG 8
#define JT 64

__global__ void __launch_bounds__(256) value_kernel(
    const float* __restrict__ emb, float* __restrict__ value)
{
    const int g  = blockIdx.x;          // [0, 2048)
    const int jt = g & 7;               // 8 j-tiles per i-group (inner: same
    const int ig = g >> 3;              //  i-rows stay hot across j-tiles)
    const int b  = ig >> 6;             // 64 i-groups per batch
    const int i0 = (ig & 63) * IG;
    const int t  = threadIdx.x;
    const int d4 = t & 31;
    const int jl = t >> 5;

    const f4* __restrict__ eb4 = (const f4*)(emb + (size_t)b * Nq * Dq);

    // a-rows for this block's 8 i's: one f4 per i per thread (32 VGPR).
    f4 a[IG];
    #pragma unroll
    for (int i = 0; i < IG; ++i) a[i] = eb4[(i0 + i) * 32 + d4];

    f4* __restrict__ out0 = (f4*)(value + (size_t)(b * Nq + i0) * Nq * Dq);
    const int j0 = jt * JT;

    #pragma unroll
    for (int jj = 0; jj < JT; jj += 8) {
        const int j = j0 + jj + jl;
        const f4 v = eb4[j * 32 + d4];
        const int off = j * 32 + d4;
        #pragma unroll
        for (int i = 0; i < IG; ++i) {
            __builtin_nontemporal_store(a[i] * v, out0 + (size_t)i * (Nq * 32) + off);
        }
    }
}

extern "C" void kernel_launch(void* const* d_in, const int* in_sizes, int n_in,
                              void* d_out, int out_size, void* d_ws, size_t ws_size,
                              hipStream_t stream) {
    const float* emb    = (const float*)d_in[0];
    const float* att_w  = (const float*)d_in[1];
    const float* att_b  = (const float*)d_in[2];
    const float* gamma  = (const float*)d_in[3];
    const float* beta   = (const float*)d_in[4];

    float* alphas = (float*)d_out;                              // B*N*N
    float* value  = (float*)d_out + (size_t)Bq * Nq * Nq;       // B*N*N*D

    float* sq = (float*)d_ws;           // B*N
    float* sk = sq + Bq * Nq;           // B*N

    scores_kernel<<<Bq * Nq / 4, 256, 0, stream>>>(emb, att_w, gamma, beta, sq, sk);
    softmax_kernel<<<Bq * Nq, 256, 0, stream>>>(sq, sk, att_b, alphas);
    value_kernel<<<(Bq * Nq / IG) * (Nq / JT), 256, 0, stream>>>(emb, value);
}